// Round 1
// baseline (12621.277 us; speedup 1.0000x reference)
//
#include <hip/hip_runtime.h>

#define N_NODES 100000
#define F_IN 128
#define HID 256
#define NCLS 64
#define N_EDGES 1600000

// ---------------------------------------------------------------------------
// Norm precompute
// ---------------------------------------------------------------------------
__global__ void k_init_deg(float* __restrict__ deg, int n) {
    int i = blockIdx.x * 256 + threadIdx.x;
    if (i < n) deg[i] = 1.0f;   // self-loop weight
}

__global__ void k_deg(const int* __restrict__ dst, const float* __restrict__ w,
                      float* __restrict__ deg, int e) {
    int i = blockIdx.x * 256 + threadIdx.x;
    if (i < e) atomicAdd(&deg[dst[i]], w[i]);
}

__global__ void k_dis(float* __restrict__ deg, float* __restrict__ selfnorm, int n) {
    int i = blockIdx.x * 256 + threadIdx.x;
    if (i < n) {
        float d = rsqrtf(deg[i]);   // deg >= 1 always (self-loop), no zero guard
        deg[i] = d;                 // deg buffer now holds d^{-1/2}
        selfnorm[i] = d * d;
    }
}

__global__ void k_norm(const int* __restrict__ src, const int* __restrict__ dst,
                       const float* __restrict__ w, const float* __restrict__ dis,
                       float* __restrict__ normw, int e) {
    int i = blockIdx.x * 256 + threadIdx.x;
    if (i < e) normw[i] = dis[src[i]] * w[i] * dis[dst[i]];
}

// ---------------------------------------------------------------------------
// GEMM: out[n, c] = sum_k act(in[n, k]) * W[k, c]
// 64 nodes x 64 cols per 256-thread block, 4x4 register tile.
// ReLU (for layers 2/3) applied to the input while staging to LDS; bias is
// NOT applied here (it is folded into agg_init of the *previous* layer).
// ---------------------------------------------------------------------------
template <int K, int DOUT, bool RELU_IN>
__global__ __launch_bounds__(256) void gemm_kernel(const float* __restrict__ in,
                                                   const float* __restrict__ W,
                                                   float* __restrict__ out,
                                                   int nNodes) {
    constexpr int BK = 32;
    __shared__ float Ws[BK][64];    // [kk][col], stride 64 floats (16B-aligned rows)
    __shared__ float XsT[BK][68];   // [kk][node], stride 68 floats (272B, 16B-aligned)

    const int t = threadIdx.x;
    const int tx = t & 15;   // col group  (4 cols each)
    const int ty = t >> 4;   // node group (4 nodes each)
    const int nodeBase = blockIdx.x * 64;
    const int colBase = blockIdx.y * 64;

    float acc[4][4] = {};

    for (int k0 = 0; k0 < K; k0 += BK) {
        // ---- stage W tile: 32 x 64 floats ----
        {
            int r = t >> 4;            // 0..15, rows r and r+16
            int c4 = (t & 15) * 4;
            #pragma unroll
            for (int rr = 0; rr < BK; rr += 16) {
                float4 w4 = *(const float4*)&W[(size_t)(k0 + r + rr) * DOUT + colBase + c4];
                *(float4*)&Ws[r + rr][c4] = w4;
            }
        }
        // ---- stage X^T tile: 64 nodes x 32 k, transposed into [k][node] ----
        {
            int nodeOff = t >> 3;        // 0..31
            int k4 = (t & 7) * 4;        // 0..28
            #pragma unroll
            for (int p = 0; p < 2; ++p) {
                int n = nodeOff + p * 32;
                int gnode = nodeBase + n;
                int gn = gnode < nNodes ? gnode : nNodes - 1;  // clamp; discarded at store
                float4 x4 = *(const float4*)&in[(size_t)gn * K + k0 + k4];
                if (RELU_IN) {
                    x4.x = fmaxf(x4.x, 0.0f);
                    x4.y = fmaxf(x4.y, 0.0f);
                    x4.z = fmaxf(x4.z, 0.0f);
                    x4.w = fmaxf(x4.w, 0.0f);
                }
                XsT[k4 + 0][n] = x4.x;
                XsT[k4 + 1][n] = x4.y;
                XsT[k4 + 2][n] = x4.z;
                XsT[k4 + 3][n] = x4.w;
            }
        }
        __syncthreads();

        #pragma unroll
        for (int kk = 0; kk < BK; ++kk) {
            float4 b4 = *(const float4*)&Ws[kk][tx * 4];
            float4 a4 = *(const float4*)&XsT[kk][ty * 4];
            float a[4] = {a4.x, a4.y, a4.z, a4.w};
            float b[4] = {b4.x, b4.y, b4.z, b4.w};
            #pragma unroll
            for (int i = 0; i < 4; ++i)
                #pragma unroll
                for (int j = 0; j < 4; ++j)
                    acc[i][j] += a[i] * b[j];
        }
        __syncthreads();
    }

    // ---- store 4x4 tile ----
    #pragma unroll
    for (int i = 0; i < 4; ++i) {
        int n = nodeBase + ty * 4 + i;
        if (n < nNodes) {
            float4 r = make_float4(acc[i][0], acc[i][1], acc[i][2], acc[i][3]);
            *(float4*)&out[(size_t)n * DOUT + colBase + tx * 4] = r;
        }
    }
}

// ---------------------------------------------------------------------------
// Aggregation init: out[n, c] = selfnorm[n] * h[n, c] + bias[c]
// (self-loop contribution + bias; edge atomics add on top)
// ---------------------------------------------------------------------------
template <int DOUT>
__global__ void agg_init(const float* __restrict__ h, const float* __restrict__ sn,
                         const float* __restrict__ bias, float* __restrict__ out,
                         int nNodes) {
    int idx = blockIdx.x * 256 + threadIdx.x;         // float4 index
    int total = nNodes * (DOUT / 4);
    if (idx >= total) return;
    int node = idx / (DOUT / 4);
    int c4 = (idx % (DOUT / 4)) * 4;
    float s = sn[node];
    float4 hv = *(const float4*)&h[(size_t)idx * 4];
    float4 b = *(const float4*)&bias[c4];
    float4 r;
    r.x = s * hv.x + b.x;
    r.y = s * hv.y + b.y;
    r.z = s * hv.z + b.z;
    r.w = s * hv.w + b.w;
    *(float4*)&out[(size_t)idx * 4] = r;
}

// ---------------------------------------------------------------------------
// Edge aggregation: out[dst, :] += norm_e * h[src, :]
// DOUT/4 threads per edge, float4 gather + 4 scalar float atomics.
// ---------------------------------------------------------------------------
template <int DOUT>
__global__ void agg_edges(const float* __restrict__ h, const int* __restrict__ src,
                          const int* __restrict__ dst, const float* __restrict__ normw,
                          float* __restrict__ out, int nEdges) {
    constexpr int TPE = DOUT / 4;        // threads per edge
    constexpr int EPB = 256 / TPE;       // edges per block
    int e = blockIdx.x * EPB + threadIdx.x / TPE;
    if (e >= nEdges) return;
    int lane = threadIdx.x % TPE;
    int s = src[e];
    int d = dst[e];
    float w = normw[e];
    float4 hv = *(const float4*)&h[(size_t)s * DOUT + lane * 4];
    float* o = &out[(size_t)d * DOUT + lane * 4];
    atomicAdd(o + 0, w * hv.x);
    atomicAdd(o + 1, w * hv.y);
    atomicAdd(o + 2, w * hv.z);
    atomicAdd(o + 3, w * hv.w);
}

// ---------------------------------------------------------------------------
extern "C" void kernel_launch(void* const* d_in, const int* in_sizes, int n_in,
                              void* d_out, int out_size, void* d_ws, size_t ws_size,
                              hipStream_t stream) {
    const float* x  = (const float*)d_in[0];
    const int*   ei = (const int*)d_in[1];
    const float* ew = (const float*)d_in[2];
    const float* W0 = (const float*)d_in[3];
    const float* b0 = (const float*)d_in[4];
    const float* W1 = (const float*)d_in[5];
    const float* b1 = (const float*)d_in[6];
    const float* W2 = (const float*)d_in[7];
    const float* b2 = (const float*)d_in[8];
    const int* src = ei;              // edge_index[0]
    const int* dst = ei + N_EDGES;    // edge_index[1]
    float* outp = (float*)d_out;

    // workspace carve-up (floats)
    float* ws = (float*)d_ws;
    float* dis      = ws;                                   // N (deg -> d^-1/2)
    float* selfnorm = ws + N_NODES;                         // N
    float* normw    = ws + 2 * N_NODES;                     // E
    float* hbuf     = ws + 2 * N_NODES + N_EDGES;           // N*HID
    float* aggbuf   = hbuf + (size_t)N_NODES * HID;         // N*HID

    // ---- norm precompute ----
    k_init_deg<<<(N_NODES + 255) / 256, 256, 0, stream>>>(dis, N_NODES);
    k_deg<<<(N_EDGES + 255) / 256, 256, 0, stream>>>(dst, ew, dis, N_EDGES);
    k_dis<<<(N_NODES + 255) / 256, 256, 0, stream>>>(dis, selfnorm, N_NODES);
    k_norm<<<(N_EDGES + 255) / 256, 256, 0, stream>>>(src, dst, ew, dis, normw, N_EDGES);

    const int gemmBlocksX = (N_NODES + 63) / 64;   // 1563

    // ---- layer 1: x[N,128] @ W0[128,256] ----
    gemm_kernel<F_IN, HID, false><<<dim3(gemmBlocksX, HID / 64), 256, 0, stream>>>(x, W0, hbuf, N_NODES);
    agg_init<HID><<<(N_NODES * (HID / 4) + 255) / 256, 256, 0, stream>>>(hbuf, selfnorm, b0, aggbuf, N_NODES);
    agg_edges<HID><<<(N_EDGES * (HID / 4) + 255) / 256, 256, 0, stream>>>(hbuf, src, dst, normw, aggbuf, N_EDGES);

    // ---- layer 2: relu(agg1)[N,256] @ W1[256,256] ----
    gemm_kernel<HID, HID, true><<<dim3(gemmBlocksX, HID / 64), 256, 0, stream>>>(aggbuf, W1, hbuf, N_NODES);
    agg_init<HID><<<(N_NODES * (HID / 4) + 255) / 256, 256, 0, stream>>>(hbuf, selfnorm, b1, aggbuf, N_NODES);
    agg_edges<HID><<<(N_EDGES * (HID / 4) + 255) / 256, 256, 0, stream>>>(hbuf, src, dst, normw, aggbuf, N_EDGES);

    // ---- layer 3: relu(agg2)[N,256] @ W2[256,64] -> d_out ----
    gemm_kernel<HID, NCLS, true><<<dim3(gemmBlocksX, NCLS / 64), 256, 0, stream>>>(aggbuf, W2, hbuf, N_NODES);
    agg_init<NCLS><<<(N_NODES * (NCLS / 4) + 255) / 256, 256, 0, stream>>>(hbuf, selfnorm, b2, outp, N_NODES);
    agg_edges<NCLS><<<(N_EDGES * (NCLS / 4) + 255) / 256, 256, 0, stream>>>(hbuf, src, dst, normw, outp, N_EDGES);
}

// Round 2
// 1214.114 us; speedup vs baseline: 10.3955x; 10.3955x over previous
//
#include <hip/hip_runtime.h>

#define N_NODES 100000
#define F_IN 128
#define HID 256
#define NCLS 64
#define N_EDGES 1600000

// ---------------------------------------------------------------------------
// Norm + CSR precompute
// ---------------------------------------------------------------------------
__global__ void k_init(float* __restrict__ deg, int* __restrict__ cnt, int n) {
    int i = blockIdx.x * 256 + threadIdx.x;
    if (i < n) { deg[i] = 1.0f; cnt[i] = 0; }   // self-loop weight; zero edge count
}

__global__ void k_deg(const int* __restrict__ dst, const float* __restrict__ w,
                      float* __restrict__ deg, int* __restrict__ cnt, int e) {
    int i = blockIdx.x * 256 + threadIdx.x;
    if (i < e) {
        int d = dst[i];
        atomicAdd(&deg[d], w[i]);
        atomicAdd(&cnt[d], 1);
    }
}

__global__ void k_dis(float* __restrict__ deg, float* __restrict__ selfnorm, int n) {
    int i = blockIdx.x * 256 + threadIdx.x;
    if (i < n) {
        float d = rsqrtf(deg[i]);   // deg >= 1 always (self-loop)
        deg[i] = d;                 // deg buffer now holds d^{-1/2}
        selfnorm[i] = d * d;
    }
}

// --- 3-kernel exclusive scan of cnt[] -> row[] (100000 elements) ---
__global__ void k_scan1(const int* __restrict__ cnt, int* __restrict__ incl,
                        int* __restrict__ bsum, int n) {
    __shared__ int s[256];
    int t = threadIdx.x;
    int i = blockIdx.x * 256 + t;
    int v = (i < n) ? cnt[i] : 0;
    s[t] = v;
    __syncthreads();
    #pragma unroll
    for (int off = 1; off < 256; off <<= 1) {
        int x = (t >= off) ? s[t - off] : 0;
        __syncthreads();
        s[t] += x;
        __syncthreads();
    }
    if (i < n) incl[i] = s[t];            // block-local inclusive scan
    if (t == 255) bsum[blockIdx.x] = s[255];
}

__global__ void k_scan2(const int* __restrict__ bsum, int* __restrict__ boff, int nb) {
    __shared__ int s[512];
    int t = threadIdx.x;
    int v = (t < nb) ? bsum[t] : 0;
    s[t] = v;
    __syncthreads();
    #pragma unroll
    for (int off = 1; off < 512; off <<= 1) {
        int x = (t >= off) ? s[t - off] : 0;
        __syncthreads();
        s[t] += x;
        __syncthreads();
    }
    if (t < nb) boff[t] = s[t] - v;       // exclusive block offsets
}

// row[i] = global exclusive start (in-place over incl)
__global__ void k_scan3(int* __restrict__ row, const int* __restrict__ cnt,
                        const int* __restrict__ boff, int n) {
    int i = blockIdx.x * 256 + threadIdx.x;
    if (i < n) row[i] = row[i] - cnt[i] + boff[i >> 8];
}

// scatter edges into CSR; row[] acts as cursor (ends as row_end = start + cnt)
__global__ void k_scatter(const int* __restrict__ src, const int* __restrict__ dst,
                          const float* __restrict__ w, const float* __restrict__ dis,
                          int* __restrict__ row, int* __restrict__ csr_src,
                          float* __restrict__ csr_w, int e) {
    int i = blockIdx.x * 256 + threadIdx.x;
    if (i < e) {
        int s = src[i], d = dst[i];
        float nw = dis[s] * w[i] * dis[d];
        int pos = atomicAdd(&row[d], 1);
        csr_src[pos] = s;
        csr_w[pos] = nw;
    }
}

// ---------------------------------------------------------------------------
// GEMM: out[n, c] = sum_k act(in[n, k]) * W[k, c]
// 64 nodes x 64 cols per 256-thread block, 4x4 register tile.
// ReLU (for layers 2/3) applied to the input while staging to LDS; bias is
// folded into the aggregation kernel of the same layer.
// ---------------------------------------------------------------------------
template <int K, int DOUT, bool RELU_IN>
__global__ __launch_bounds__(256) void gemm_kernel(const float* __restrict__ in,
                                                   const float* __restrict__ W,
                                                   float* __restrict__ out,
                                                   int nNodes) {
    constexpr int BK = 32;
    __shared__ float Ws[BK][64];
    __shared__ float XsT[BK][68];

    const int t = threadIdx.x;
    const int tx = t & 15;
    const int ty = t >> 4;
    const int nodeBase = blockIdx.x * 64;
    const int colBase = blockIdx.y * 64;

    float acc[4][4] = {};

    for (int k0 = 0; k0 < K; k0 += BK) {
        {
            int r = t >> 4;
            int c4 = (t & 15) * 4;
            #pragma unroll
            for (int rr = 0; rr < BK; rr += 16) {
                float4 w4 = *(const float4*)&W[(size_t)(k0 + r + rr) * DOUT + colBase + c4];
                *(float4*)&Ws[r + rr][c4] = w4;
            }
        }
        {
            int nodeOff = t >> 3;
            int k4 = (t & 7) * 4;
            #pragma unroll
            for (int p = 0; p < 2; ++p) {
                int n = nodeOff + p * 32;
                int gnode = nodeBase + n;
                int gn = gnode < nNodes ? gnode : nNodes - 1;
                float4 x4 = *(const float4*)&in[(size_t)gn * K + k0 + k4];
                if (RELU_IN) {
                    x4.x = fmaxf(x4.x, 0.0f);
                    x4.y = fmaxf(x4.y, 0.0f);
                    x4.z = fmaxf(x4.z, 0.0f);
                    x4.w = fmaxf(x4.w, 0.0f);
                }
                XsT[k4 + 0][n] = x4.x;
                XsT[k4 + 1][n] = x4.y;
                XsT[k4 + 2][n] = x4.z;
                XsT[k4 + 3][n] = x4.w;
            }
        }
        __syncthreads();

        #pragma unroll
        for (int kk = 0; kk < BK; ++kk) {
            float4 b4 = *(const float4*)&Ws[kk][tx * 4];
            float4 a4 = *(const float4*)&XsT[kk][ty * 4];
            float a[4] = {a4.x, a4.y, a4.z, a4.w};
            float b[4] = {b4.x, b4.y, b4.z, b4.w};
            #pragma unroll
            for (int i = 0; i < 4; ++i)
                #pragma unroll
                for (int j = 0; j < 4; ++j)
                    acc[i][j] += a[i] * b[j];
        }
        __syncthreads();
    }

    #pragma unroll
    for (int i = 0; i < 4; ++i) {
        int n = nodeBase + ty * 4 + i;
        if (n < nNodes) {
            float4 r = make_float4(acc[i][0], acc[i][1], acc[i][2], acc[i][3]);
            *(float4*)&out[(size_t)n * DOUT + colBase + tx * 4] = r;
        }
    }
}

// ---------------------------------------------------------------------------
// CSR aggregation: out[d,:] = selfnorm[d]*h[d,:] + bias + sum_e w_e * h[src_e,:]
// TPN threads per node, each handling 4 contiguous columns (float4).
// row[] holds row_end (post-scatter cursor); start = end - cnt.
// ---------------------------------------------------------------------------
template <int DOUT, int TPN>
__global__ __launch_bounds__(256) void agg_csr(const float* __restrict__ h,
                                               const int* __restrict__ csr_src,
                                               const float* __restrict__ csr_w,
                                               const int* __restrict__ row,
                                               const int* __restrict__ cnt,
                                               const float* __restrict__ sn,
                                               const float* __restrict__ bias,
                                               float* __restrict__ out, int nNodes) {
    constexpr int NPB = 256 / TPN;
    int node = blockIdx.x * NPB + threadIdx.x / TPN;
    if (node >= nNodes) return;
    int lane = threadIdx.x % TPN;
    const float4* h4 = (const float4*)h;
    int col = lane;                      // float4 column index
    size_t rowStride = DOUT / 4;

    float s = sn[node];
    float4 hv = h4[(size_t)node * rowStride + col];
    float4 b = *(const float4*)&bias[col * 4];
    float4 acc;
    acc.x = s * hv.x + b.x;
    acc.y = s * hv.y + b.y;
    acc.z = s * hv.z + b.z;
    acc.w = s * hv.w + b.w;

    int end = row[node];
    int start = end - cnt[node];
    int e = start;
    for (; e + 1 < end; e += 2) {
        int s0 = csr_src[e], s1 = csr_src[e + 1];
        float w0 = csr_w[e], w1 = csr_w[e + 1];
        float4 a0 = h4[(size_t)s0 * rowStride + col];
        float4 a1 = h4[(size_t)s1 * rowStride + col];
        acc.x += w0 * a0.x + w1 * a1.x;
        acc.y += w0 * a0.y + w1 * a1.y;
        acc.z += w0 * a0.z + w1 * a1.z;
        acc.w += w0 * a0.w + w1 * a1.w;
    }
    if (e < end) {
        int s0 = csr_src[e];
        float w0 = csr_w[e];
        float4 a0 = h4[(size_t)s0 * rowStride + col];
        acc.x += w0 * a0.x;
        acc.y += w0 * a0.y;
        acc.z += w0 * a0.z;
        acc.w += w0 * a0.w;
    }
    ((float4*)out)[(size_t)node * rowStride + col] = acc;
}

// ---------------------------------------------------------------------------
extern "C" void kernel_launch(void* const* d_in, const int* in_sizes, int n_in,
                              void* d_out, int out_size, void* d_ws, size_t ws_size,
                              hipStream_t stream) {
    const float* x  = (const float*)d_in[0];
    const int*   ei = (const int*)d_in[1];
    const float* ew = (const float*)d_in[2];
    const float* W0 = (const float*)d_in[3];
    const float* b0 = (const float*)d_in[4];
    const float* W1 = (const float*)d_in[5];
    const float* b1 = (const float*)d_in[6];
    const float* W2 = (const float*)d_in[7];
    const float* b2 = (const float*)d_in[8];
    const int* src = ei;              // edge_index[0]
    const int* dst = ei + N_EDGES;    // edge_index[1]
    float* outp = (float*)d_out;

    // workspace carve-up (4B units)
    char* ws = (char*)d_ws;
    float* dis      = (float*)ws;                       ws += N_NODES * 4;
    float* selfnorm = (float*)ws;                       ws += N_NODES * 4;
    int*   cnt      = (int*)ws;                         ws += N_NODES * 4;
    int*   row      = (int*)ws;                         ws += N_NODES * 4;
    int*   bsum     = (int*)ws;                         ws += 512 * 4;
    int*   boff     = (int*)ws;                         ws += 512 * 4;
    int*   csr_src  = (int*)ws;                         ws += (size_t)N_EDGES * 4;
    float* csr_w    = (float*)ws;                       ws += (size_t)N_EDGES * 4;
    float* hbuf     = (float*)ws;                       ws += (size_t)N_NODES * HID * 4;
    float* aggbuf   = (float*)ws;

    const int nb = (N_NODES + 255) / 256;   // 391 scan blocks
    const int eb = (N_EDGES + 255) / 256;

    // ---- norm + CSR build ----
    k_init<<<nb, 256, 0, stream>>>(dis, cnt, N_NODES);
    k_deg<<<eb, 256, 0, stream>>>(dst, ew, dis, cnt, N_EDGES);
    k_dis<<<nb, 256, 0, stream>>>(dis, selfnorm, N_NODES);
    k_scan1<<<nb, 256, 0, stream>>>(cnt, row, bsum, N_NODES);
    k_scan2<<<1, 512, 0, stream>>>(bsum, boff, nb);
    k_scan3<<<nb, 256, 0, stream>>>(row, cnt, boff, N_NODES);
    k_scatter<<<eb, 256, 0, stream>>>(src, dst, ew, dis, row, csr_src, csr_w, N_EDGES);
    // row[] now holds row_end per node

    const int gemmBlocksX = (N_NODES + 63) / 64;

    // ---- layer 1: x[N,128] @ W0 -> hbuf; aggregate -> aggbuf ----
    gemm_kernel<F_IN, HID, false><<<dim3(gemmBlocksX, HID / 64), 256, 0, stream>>>(x, W0, hbuf, N_NODES);
    agg_csr<HID, 64><<<(N_NODES + 3) / 4, 256, 0, stream>>>(hbuf, csr_src, csr_w, row, cnt, selfnorm, b0, aggbuf, N_NODES);

    // ---- layer 2: relu(aggbuf) @ W1 -> hbuf; aggregate -> aggbuf (safe: gemm fully reads before agg writes? no — separate buffers) ----
    gemm_kernel<HID, HID, true><<<dim3(gemmBlocksX, HID / 64), 256, 0, stream>>>(aggbuf, W1, hbuf, N_NODES);
    agg_csr<HID, 64><<<(N_NODES + 3) / 4, 256, 0, stream>>>(hbuf, csr_src, csr_w, row, cnt, selfnorm, b1, aggbuf, N_NODES);

    // ---- layer 3: relu(aggbuf) @ W2 -> hbuf; aggregate -> d_out ----
    gemm_kernel<HID, NCLS, true><<<dim3(gemmBlocksX, NCLS / 64), 256, 0, stream>>>(aggbuf, W2, hbuf, N_NODES);
    agg_csr<NCLS, 16><<<(N_NODES + 15) / 16, 256, 0, stream>>>(hbuf, csr_src, csr_w, row, cnt, selfnorm, b2, outp, N_NODES);
}

// Round 3
// 750.074 us; speedup vs baseline: 16.8267x; 1.6187x over previous
//
#include <hip/hip_runtime.h>

#define N_NODES 100000
#define F_IN 128
#define HID 256
#define NCLS 64
#define N_EDGES 1600000

typedef _Float16 f16;
typedef f16 half8 __attribute__((ext_vector_type(8)));
typedef f16 half4 __attribute__((ext_vector_type(4)));
typedef float f32x4 __attribute__((ext_vector_type(4)));

// ---------------------------------------------------------------------------
// Norm + CSR precompute
// ---------------------------------------------------------------------------
__global__ void k_init(float* __restrict__ deg, int* __restrict__ cnt, int n) {
    int i = blockIdx.x * 256 + threadIdx.x;
    if (i < n) { deg[i] = 1.0f; cnt[i] = 0; }
}

__global__ void k_deg(const int* __restrict__ dst, const float* __restrict__ w,
                      float* __restrict__ deg, int* __restrict__ cnt, int e) {
    int i = blockIdx.x * 256 + threadIdx.x;
    if (i < e) {
        int d = dst[i];
        atomicAdd(&deg[d], w[i]);
        atomicAdd(&cnt[d], 1);
    }
}

__global__ void k_dis(float* __restrict__ deg, float* __restrict__ selfnorm, int n) {
    int i = blockIdx.x * 256 + threadIdx.x;
    if (i < n) {
        float d = rsqrtf(deg[i]);
        deg[i] = d;
        selfnorm[i] = d * d;
    }
}

__global__ void k_scan1(const int* __restrict__ cnt, int* __restrict__ incl,
                        int* __restrict__ bsum, int n) {
    __shared__ int s[256];
    int t = threadIdx.x;
    int i = blockIdx.x * 256 + t;
    int v = (i < n) ? cnt[i] : 0;
    s[t] = v;
    __syncthreads();
    #pragma unroll
    for (int off = 1; off < 256; off <<= 1) {
        int x = (t >= off) ? s[t - off] : 0;
        __syncthreads();
        s[t] += x;
        __syncthreads();
    }
    if (i < n) incl[i] = s[t];
    if (t == 255) bsum[blockIdx.x] = s[255];
}

__global__ void k_scan2(const int* __restrict__ bsum, int* __restrict__ boff, int nb) {
    __shared__ int s[512];
    int t = threadIdx.x;
    int v = (t < nb) ? bsum[t] : 0;
    s[t] = v;
    __syncthreads();
    #pragma unroll
    for (int off = 1; off < 512; off <<= 1) {
        int x = (t >= off) ? s[t - off] : 0;
        __syncthreads();
        s[t] += x;
        __syncthreads();
    }
    if (t < nb) boff[t] = s[t] - v;
}

__global__ void k_scan3(int* __restrict__ row, const int* __restrict__ cnt,
                        const int* __restrict__ boff, int n) {
    int i = blockIdx.x * 256 + threadIdx.x;
    if (i < n) row[i] = row[i] - cnt[i] + boff[i >> 8];
}

__global__ void k_scatter(const int* __restrict__ src, const int* __restrict__ dst,
                          const float* __restrict__ w, const float* __restrict__ dis,
                          int* __restrict__ row, int* __restrict__ csr_src,
                          float* __restrict__ csr_w, int e) {
    int i = blockIdx.x * 256 + threadIdx.x;
    if (i < e) {
        int s = src[i], d = dst[i];
        float nw = dis[s] * w[i] * dis[d];
        int pos = atomicAdd(&row[d], 1);
        csr_src[pos] = s;
        csr_w[pos] = nw;
    }
}

// ---------------------------------------------------------------------------
// dtype conversion helpers
// ---------------------------------------------------------------------------
__global__ void k_f32_to_f16(const float* __restrict__ src, f16* __restrict__ dst, int n4) {
    int i = blockIdx.x * 256 + threadIdx.x;
    if (i < n4) {
        float4 v = *(const float4*)&src[(size_t)i * 4];
        half4 o;
        o[0] = (f16)v.x; o[1] = (f16)v.y; o[2] = (f16)v.z; o[3] = (f16)v.w;
        *(half4*)&dst[(size_t)i * 4] = o;
    }
}

// W[K][D] fp32 -> Wt[D][K] fp16 (tiny, once per call)
__global__ void k_wt(const float* __restrict__ W, f16* __restrict__ Wt, int K, int D) {
    int i = blockIdx.x * 256 + threadIdx.x;
    if (i < K * D) {
        int k = i / D, d = i % D;
        Wt[d * K + k] = (f16)W[i];
    }
}

// ---------------------------------------------------------------------------
// MFMA GEMM: out[n, c] = sum_k act(in[n, k]) * W[k, c]     (fp16 in, fp16 out)
// Block tile 128x64, 4 waves, each wave 32 rows x 64 cols = 2x4 mfma 16x16x32.
// A and B both staged in LDS as [outer][k] so fragments are contiguous b128.
// ---------------------------------------------------------------------------
template <int K, int DOUT, bool RELU_IN>
__global__ __launch_bounds__(256) void gemm_mfma(const f16* __restrict__ in,
                                                 const f16* __restrict__ Wt,  // [DOUT][K]
                                                 f16* __restrict__ out,
                                                 int nNodes) {
    constexpr int BM = 128, BN = 64, BK = 32;
    constexpr int AP = 40;   // padded k-stride (f16) for A/B tiles
    constexpr int CP = 72;   // padded col-stride for C tile
    constexpr int SMEM = (BM * AP + BN * AP) > (BM * CP) ? (BM * AP + BN * AP) : (BM * CP);
    __shared__ f16 smem[SMEM];
    f16* As = smem;               // [BM][AP]
    f16* Bs = smem + BM * AP;     // [BN][AP]

    const int t = threadIdx.x;
    const int w = t >> 6;
    const int lane = t & 63;
    const int quad = lane >> 4;
    const int l16 = lane & 15;
    const int nodeBase = blockIdx.x * BM;
    const int colBase = blockIdx.y * BN;

    f32x4 acc[2][4] = {};

    for (int k0 = 0; k0 < K; k0 += BK) {
        // stage A: 128 rows x 32 k
        {
            int koff = (t & 3) * 8;
            #pragma unroll
            for (int p = 0; p < 2; ++p) {
                int r = (t >> 2) + p * 64;
                int gn = nodeBase + r;
                if (gn >= nNodes) gn = nNodes - 1;
                half8 v = *(const half8*)&in[(size_t)gn * K + k0 + koff];
                if (RELU_IN) {
                    #pragma unroll
                    for (int i = 0; i < 8; ++i) v[i] = v[i] > (f16)0.f ? v[i] : (f16)0.f;
                }
                *(half8*)&As[r * AP + koff] = v;
            }
        }
        // stage B: 64 cols x 32 k (from Wt, already [DOUT][K])
        {
            int koff = (t & 3) * 8;
            int c = t >> 2;
            half8 v = *(const half8*)&Wt[(size_t)(colBase + c) * K + k0 + koff];
            *(half8*)&Bs[c * AP + koff] = v;
        }
        __syncthreads();

        half8 a[2];
        #pragma unroll
        for (int rt = 0; rt < 2; ++rt)
            a[rt] = *(const half8*)&As[(w * 32 + rt * 16 + l16) * AP + quad * 8];
        #pragma unroll
        for (int ct = 0; ct < 4; ++ct) {
            half8 b = *(const half8*)&Bs[(ct * 16 + l16) * AP + quad * 8];
            acc[0][ct] = __builtin_amdgcn_mfma_f32_16x16x32_f16(a[0], b, acc[0][ct], 0, 0, 0);
            acc[1][ct] = __builtin_amdgcn_mfma_f32_16x16x32_f16(a[1], b, acc[1][ct], 0, 0, 0);
        }
        __syncthreads();
    }

    // epilogue: C frags -> LDS (fp16) -> coalesced global stores
    f16* Cs = smem;   // alias; safe after the loop's final __syncthreads
    #pragma unroll
    for (int rt = 0; rt < 2; ++rt)
        #pragma unroll
        for (int ct = 0; ct < 4; ++ct)
            #pragma unroll
            for (int r = 0; r < 4; ++r) {
                int rr = w * 32 + rt * 16 + quad * 4 + r;
                int cc = ct * 16 + l16;
                Cs[rr * CP + cc] = (f16)acc[rt][ct][r];
            }
    __syncthreads();
    #pragma unroll
    for (int p = 0; p < 4; ++p) {
        int r = (t >> 3) + p * 32;
        int gn = nodeBase + r;
        int chunk = (t & 7) * 8;
        if (gn < nNodes)
            *(half8*)&out[(size_t)gn * DOUT + colBase + chunk] =
                *(const half8*)&Cs[r * CP + chunk];
    }
}

// ---------------------------------------------------------------------------
// CSR aggregation (fp16 h): out[d,:] = sn[d]*h[d,:] + bias + sum_e w_e*h[src_e,:]
// TPN lanes per node, 8 cols (one half8 = 16B) per lane, fp32 accumulate.
// ---------------------------------------------------------------------------
template <int DOUT, int TPN, bool OUT_F32>
__global__ __launch_bounds__(256) void agg_csr(const f16* __restrict__ h,
                                               const int* __restrict__ csr_src,
                                               const float* __restrict__ csr_w,
                                               const int* __restrict__ row,
                                               const int* __restrict__ cnt,
                                               const float* __restrict__ sn,
                                               const float* __restrict__ bias,
                                               void* __restrict__ outv, int nNodes) {
    constexpr int NPB = 256 / TPN;
    int node = blockIdx.x * NPB + threadIdx.x / TPN;
    if (node >= nNodes) return;
    int lane = threadIdx.x % TPN;
    int col = lane * 8;

    float s = sn[node];
    half8 hv = *(const half8*)&h[(size_t)node * DOUT + col];
    float acc[8];
    #pragma unroll
    for (int i = 0; i < 8; ++i) acc[i] = s * (float)hv[i] + bias[col + i];

    int end = row[node];
    int e = end - cnt[node];
    for (; e + 1 < end; e += 2) {
        int s0 = csr_src[e], s1 = csr_src[e + 1];
        float w0 = csr_w[e], w1 = csr_w[e + 1];
        half8 a0 = *(const half8*)&h[(size_t)s0 * DOUT + col];
        half8 a1 = *(const half8*)&h[(size_t)s1 * DOUT + col];
        #pragma unroll
        for (int i = 0; i < 8; ++i) acc[i] += w0 * (float)a0[i] + w1 * (float)a1[i];
    }
    if (e < end) {
        int s0 = csr_src[e];
        float w0 = csr_w[e];
        half8 a0 = *(const half8*)&h[(size_t)s0 * DOUT + col];
        #pragma unroll
        for (int i = 0; i < 8; ++i) acc[i] += w0 * (float)a0[i];
    }

    if (OUT_F32) {
        float* out = (float*)outv;
        float4 r0 = make_float4(acc[0], acc[1], acc[2], acc[3]);
        float4 r1 = make_float4(acc[4], acc[5], acc[6], acc[7]);
        *(float4*)&out[(size_t)node * DOUT + col] = r0;
        *(float4*)&out[(size_t)node * DOUT + col + 4] = r1;
    } else {
        f16* out = (f16*)outv;
        half8 o;
        #pragma unroll
        for (int i = 0; i < 8; ++i) o[i] = (f16)acc[i];
        *(half8*)&out[(size_t)node * DOUT + col] = o;
    }
}

// ---------------------------------------------------------------------------
extern "C" void kernel_launch(void* const* d_in, const int* in_sizes, int n_in,
                              void* d_out, int out_size, void* d_ws, size_t ws_size,
                              hipStream_t stream) {
    const float* x  = (const float*)d_in[0];
    const int*   ei = (const int*)d_in[1];
    const float* ew = (const float*)d_in[2];
    const float* W0 = (const float*)d_in[3];
    const float* b0 = (const float*)d_in[4];
    const float* W1 = (const float*)d_in[5];
    const float* b1 = (const float*)d_in[6];
    const float* W2 = (const float*)d_in[7];
    const float* b2 = (const float*)d_in[8];
    const int* src = ei;
    const int* dst = ei + N_EDGES;
    float* outp = (float*)d_out;

    // workspace carve-up
    char* ws = (char*)d_ws;
    float* dis      = (float*)ws;  ws += N_NODES * 4;
    float* selfnorm = (float*)ws;  ws += N_NODES * 4;
    int*   cnt      = (int*)ws;    ws += N_NODES * 4;
    int*   row      = (int*)ws;    ws += N_NODES * 4;
    int*   bsum     = (int*)ws;    ws += 512 * 4;
    int*   boff     = (int*)ws;    ws += 512 * 4;
    int*   csr_src  = (int*)ws;    ws += (size_t)N_EDGES * 4;
    float* csr_w    = (float*)ws;  ws += (size_t)N_EDGES * 4;
    f16*   xh       = (f16*)ws;    ws += (size_t)N_NODES * F_IN * 2;
    f16*   Wt0      = (f16*)ws;    ws += F_IN * HID * 2;
    f16*   Wt1      = (f16*)ws;    ws += HID * HID * 2;
    f16*   Wt2      = (f16*)ws;    ws += HID * NCLS * 2;
    f16*   hbuf     = (f16*)ws;    ws += (size_t)N_NODES * HID * 2;
    f16*   aggbuf   = (f16*)ws;    ws += (size_t)N_NODES * HID * 2;

    const int nb = (N_NODES + 255) / 256;
    const int eb = (N_EDGES + 255) / 256;

    // ---- norm + CSR build ----
    k_init<<<nb, 256, 0, stream>>>(dis, cnt, N_NODES);
    k_deg<<<eb, 256, 0, stream>>>(dst, ew, dis, cnt, N_EDGES);
    k_dis<<<nb, 256, 0, stream>>>(dis, selfnorm, N_NODES);
    k_scan1<<<nb, 256, 0, stream>>>(cnt, row, bsum, N_NODES);
    k_scan2<<<1, 512, 0, stream>>>(bsum, boff, nb);
    k_scan3<<<nb, 256, 0, stream>>>(row, cnt, boff, N_NODES);
    k_scatter<<<eb, 256, 0, stream>>>(src, dst, ew, dis, row, csr_src, csr_w, N_EDGES);

    // ---- fp16 conversions ----
    k_f32_to_f16<<<(N_NODES * (F_IN / 4) + 255) / 256, 256, 0, stream>>>(x, xh, N_NODES * (F_IN / 4));
    k_wt<<<(F_IN * HID + 255) / 256, 256, 0, stream>>>(W0, Wt0, F_IN, HID);
    k_wt<<<(HID * HID + 255) / 256, 256, 0, stream>>>(W1, Wt1, HID, HID);
    k_wt<<<(HID * NCLS + 255) / 256, 256, 0, stream>>>(W2, Wt2, HID, NCLS);

    const int gX = (N_NODES + 127) / 128;

    // ---- layer 1 ----
    gemm_mfma<F_IN, HID, false><<<dim3(gX, HID / 64), 256, 0, stream>>>(xh, Wt0, hbuf, N_NODES);
    agg_csr<HID, 32, false><<<(N_NODES + 7) / 8, 256, 0, stream>>>(hbuf, csr_src, csr_w, row, cnt, selfnorm, b0, aggbuf, N_NODES);

    // ---- layer 2 ----
    gemm_mfma<HID, HID, true><<<dim3(gX, HID / 64), 256, 0, stream>>>(aggbuf, Wt1, hbuf, N_NODES);
    agg_csr<HID, 32, false><<<(N_NODES + 7) / 8, 256, 0, stream>>>(hbuf, csr_src, csr_w, row, cnt, selfnorm, b1, aggbuf, N_NODES);

    // ---- layer 3 ----
    gemm_mfma<HID, NCLS, true><<<dim3(gX, NCLS / 64), 256, 0, stream>>>(aggbuf, Wt2, hbuf, N_NODES);
    agg_csr<NCLS, 8, true><<<(N_NODES + 31) / 32, 256, 0, stream>>>(hbuf, csr_src, csr_w, row, cnt, selfnorm, b2, outp, N_NODES);
}

// Round 4
// 598.723 us; speedup vs baseline: 21.0803x; 1.2528x over previous
//
#include <hip/hip_runtime.h>

#define N_NODES 100000
#define F_IN 128
#define HID 256
#define NCLS 64
#define N_EDGES 1600000

typedef _Float16 f16;
typedef f16 half8 __attribute__((ext_vector_type(8)));
typedef f16 half4 __attribute__((ext_vector_type(4)));
typedef float f32x4 __attribute__((ext_vector_type(4)));

#define FIXED_SCALE 67108864.0f   // 2^26

// ---------------------------------------------------------------------------
// Norm + CSR precompute
// degp[i]: packed u64 = (edge_count << 40) | fixed_point_26(weighted_deg)
// ---------------------------------------------------------------------------
__global__ void k_init(unsigned long long* __restrict__ degp, int n) {
    int i = blockIdx.x * 256 + threadIdx.x;
    if (i < n) degp[i] = (unsigned long long)(1u << 26);   // self-loop weight 1.0, count 0
}

__global__ void k_deg(const int* __restrict__ dst, const float* __restrict__ w,
                      unsigned long long* __restrict__ degp, int e) {
    int i = blockIdx.x * 256 + threadIdx.x;
    if (i < e) {
        unsigned long long c = (1ULL << 40) |
            (unsigned long long)__float2uint_rn(w[i] * FIXED_SCALE);
        atomicAdd(&degp[dst[i]], c);
    }
}

__global__ void k_dis(const unsigned long long* __restrict__ degp,
                      float* __restrict__ dis, float* __restrict__ selfnorm,
                      int* __restrict__ cnt, int n) {
    int i = blockIdx.x * 256 + threadIdx.x;
    if (i < n) {
        unsigned long long p = degp[i];
        int c = (int)(p >> 40);
        float deg = (float)(p & ((1ULL << 40) - 1)) * (1.0f / FIXED_SCALE);
        float d = rsqrtf(deg);
        dis[i] = d;
        selfnorm[i] = d * d;
        cnt[i] = c;
    }
}

__global__ void k_scan1(const int* __restrict__ cnt, int* __restrict__ incl,
                        int* __restrict__ bsum, int n) {
    __shared__ int s[256];
    int t = threadIdx.x;
    int i = blockIdx.x * 256 + t;
    int v = (i < n) ? cnt[i] : 0;
    s[t] = v;
    __syncthreads();
    #pragma unroll
    for (int off = 1; off < 256; off <<= 1) {
        int x = (t >= off) ? s[t - off] : 0;
        __syncthreads();
        s[t] += x;
        __syncthreads();
    }
    if (i < n) incl[i] = s[t];
    if (t == 255) bsum[blockIdx.x] = s[255];
}

__global__ void k_scan2(const int* __restrict__ bsum, int* __restrict__ boff, int nb) {
    __shared__ int s[512];
    int t = threadIdx.x;
    int v = (t < nb) ? bsum[t] : 0;
    s[t] = v;
    __syncthreads();
    #pragma unroll
    for (int off = 1; off < 512; off <<= 1) {
        int x = (t >= off) ? s[t - off] : 0;
        __syncthreads();
        s[t] += x;
        __syncthreads();
    }
    if (t < nb) boff[t] = s[t] - v;
}

__global__ void k_scan3(int* __restrict__ row, const int* __restrict__ cnt,
                        const int* __restrict__ boff, int n) {
    int i = blockIdx.x * 256 + threadIdx.x;
    if (i < n) row[i] = row[i] - cnt[i] + boff[i >> 8];
}

// scatter edges into CSR (interleaved {src, w} int2); row[] acts as cursor
__global__ void k_scatter(const int* __restrict__ src, const int* __restrict__ dst,
                          const float* __restrict__ w, const float* __restrict__ dis,
                          int* __restrict__ row, int2* __restrict__ csr, int e) {
    int i = blockIdx.x * 256 + threadIdx.x;
    if (i < e) {
        int s = src[i], d = dst[i];
        float nw = dis[s] * w[i] * dis[d];
        int pos = atomicAdd(&row[d], 1);
        csr[pos] = make_int2(s, __float_as_int(nw));
    }
}

// ---------------------------------------------------------------------------
// dtype conversion helpers
// ---------------------------------------------------------------------------
__global__ void k_f32_to_f16(const float* __restrict__ src, f16* __restrict__ dst, int n4) {
    int i = blockIdx.x * 256 + threadIdx.x;
    if (i < n4) {
        float4 v = *(const float4*)&src[(size_t)i * 4];
        half4 o;
        o[0] = (f16)v.x; o[1] = (f16)v.y; o[2] = (f16)v.z; o[3] = (f16)v.w;
        *(half4*)&dst[(size_t)i * 4] = o;
    }
}

// W[K][D] fp32 -> Wt[D][K] fp16
__global__ void k_wt(const float* __restrict__ W, f16* __restrict__ Wt, int K, int D) {
    int i = blockIdx.x * 256 + threadIdx.x;
    if (i < K * D) {
        int k = i / D, d = i % D;
        Wt[d * K + k] = (f16)W[i];
    }
}

// ---------------------------------------------------------------------------
// MFMA GEMM: out[n, c] = sum_k in[n, k] * W[k, c]  (+bias, relu if BIAS_RELU)
// Block tile 128x64, 4 waves, each wave 32 rows x 64 cols = 2x4 mfma 16x16x32.
// ---------------------------------------------------------------------------
template <int K, int DOUT, bool BIAS_RELU>
__global__ __launch_bounds__(256) void gemm_mfma(const f16* __restrict__ in,
                                                 const f16* __restrict__ Wt,  // [DOUT][K]
                                                 const float* __restrict__ bias,
                                                 f16* __restrict__ out,
                                                 int nNodes) {
    constexpr int BM = 128, BN = 64, BK = 32;
    constexpr int AP = 40;
    constexpr int CP = 72;
    constexpr int SMEM = (BM * AP + BN * AP) > (BM * CP) ? (BM * AP + BN * AP) : (BM * CP);
    __shared__ f16 smem[SMEM];
    f16* As = smem;
    f16* Bs = smem + BM * AP;

    const int t = threadIdx.x;
    const int w = t >> 6;
    const int lane = t & 63;
    const int quad = lane >> 4;
    const int l16 = lane & 15;
    const int nodeBase = blockIdx.x * BM;
    const int colBase = blockIdx.y * BN;

    f32x4 acc[2][4] = {};

    for (int k0 = 0; k0 < K; k0 += BK) {
        {
            int koff = (t & 3) * 8;
            #pragma unroll
            for (int p = 0; p < 2; ++p) {
                int r = (t >> 2) + p * 64;
                int gn = nodeBase + r;
                if (gn >= nNodes) gn = nNodes - 1;
                half8 v = *(const half8*)&in[(size_t)gn * K + k0 + koff];
                *(half8*)&As[r * AP + koff] = v;
            }
        }
        {
            int koff = (t & 3) * 8;
            int c = t >> 2;
            half8 v = *(const half8*)&Wt[(size_t)(colBase + c) * K + k0 + koff];
            *(half8*)&Bs[c * AP + koff] = v;
        }
        __syncthreads();

        half8 a[2];
        #pragma unroll
        for (int rt = 0; rt < 2; ++rt)
            a[rt] = *(const half8*)&As[(w * 32 + rt * 16 + l16) * AP + quad * 8];
        #pragma unroll
        for (int ct = 0; ct < 4; ++ct) {
            half8 b = *(const half8*)&Bs[(ct * 16 + l16) * AP + quad * 8];
            acc[0][ct] = __builtin_amdgcn_mfma_f32_16x16x32_f16(a[0], b, acc[0][ct], 0, 0, 0);
            acc[1][ct] = __builtin_amdgcn_mfma_f32_16x16x32_f16(a[1], b, acc[1][ct], 0, 0, 0);
        }
        __syncthreads();
    }

    // epilogue: (+bias, relu) -> LDS (fp16) -> coalesced global stores
    float bv[4];
    #pragma unroll
    for (int ct = 0; ct < 4; ++ct)
        bv[ct] = BIAS_RELU ? bias[colBase + ct * 16 + l16] : 0.0f;

    f16* Cs = smem;
    #pragma unroll
    for (int rt = 0; rt < 2; ++rt)
        #pragma unroll
        for (int ct = 0; ct < 4; ++ct)
            #pragma unroll
            for (int r = 0; r < 4; ++r) {
                int rr = w * 32 + rt * 16 + quad * 4 + r;
                int cc = ct * 16 + l16;
                float v = acc[rt][ct][r];
                if (BIAS_RELU) v = fmaxf(v + bv[ct], 0.0f);
                Cs[rr * CP + cc] = (f16)v;
            }
    __syncthreads();
    #pragma unroll
    for (int p = 0; p < 4; ++p) {
        int r = (t >> 3) + p * 32;
        int gn = nodeBase + r;
        int chunk = (t & 7) * 8;
        if (gn < nNodes)
            *(half8*)&out[(size_t)gn * DOUT + colBase + chunk] =
                *(const half8*)&Cs[r * CP + chunk];
    }
}

// ---------------------------------------------------------------------------
// CSR aggregation (fp16 h): out[d,:] = sn[d]*h[d,:] (+bias) + sum_e w_e*h[src_e,:]
// TPN lanes per node, 8 cols (one half8 = 16B) per lane, fp32 accumulate.
// ---------------------------------------------------------------------------
template <int DOUT, int TPN, bool HAS_BIAS, bool OUT_F32>
__global__ __launch_bounds__(256) void agg_csr(const f16* __restrict__ h,
                                               const int2* __restrict__ csr,
                                               const int* __restrict__ row,
                                               const int* __restrict__ cnt,
                                               const float* __restrict__ sn,
                                               const float* __restrict__ bias,
                                               void* __restrict__ outv, int nNodes) {
    constexpr int NPB = 256 / TPN;
    int node = blockIdx.x * NPB + threadIdx.x / TPN;
    if (node >= nNodes) return;
    int lane = threadIdx.x % TPN;
    int col = lane * 8;

    float s = sn[node];
    half8 hv = *(const half8*)&h[(size_t)node * DOUT + col];
    float acc[8];
    #pragma unroll
    for (int i = 0; i < 8; ++i)
        acc[i] = s * (float)hv[i] + (HAS_BIAS ? bias[col + i] : 0.0f);

    int end = row[node];
    int e = end - cnt[node];
    for (; e + 1 < end; e += 2) {
        int2 e0 = csr[e], e1 = csr[e + 1];
        float w0 = __int_as_float(e0.y), w1 = __int_as_float(e1.y);
        half8 a0 = *(const half8*)&h[(size_t)e0.x * DOUT + col];
        half8 a1 = *(const half8*)&h[(size_t)e1.x * DOUT + col];
        #pragma unroll
        for (int i = 0; i < 8; ++i) acc[i] += w0 * (float)a0[i] + w1 * (float)a1[i];
    }
    if (e < end) {
        int2 e0 = csr[e];
        float w0 = __int_as_float(e0.y);
        half8 a0 = *(const half8*)&h[(size_t)e0.x * DOUT + col];
        #pragma unroll
        for (int i = 0; i < 8; ++i) acc[i] += w0 * (float)a0[i];
    }

    if (OUT_F32) {
        float* out = (float*)outv;
        float4 r0 = make_float4(acc[0], acc[1], acc[2], acc[3]);
        float4 r1 = make_float4(acc[4], acc[5], acc[6], acc[7]);
        *(float4*)&out[(size_t)node * DOUT + col] = r0;
        *(float4*)&out[(size_t)node * DOUT + col + 4] = r1;
    } else {
        f16* out = (f16*)outv;
        half8 o;
        #pragma unroll
        for (int i = 0; i < 8; ++i) o[i] = (f16)acc[i];
        *(half8*)&out[(size_t)node * DOUT + col] = o;
    }
}

// ---------------------------------------------------------------------------
extern "C" void kernel_launch(void* const* d_in, const int* in_sizes, int n_in,
                              void* d_out, int out_size, void* d_ws, size_t ws_size,
                              hipStream_t stream) {
    const float* x  = (const float*)d_in[0];
    const int*   ei = (const int*)d_in[1];
    const float* ew = (const float*)d_in[2];
    const float* W0 = (const float*)d_in[3];
    const float* b0 = (const float*)d_in[4];
    const float* W1 = (const float*)d_in[5];
    const float* b1 = (const float*)d_in[6];
    const float* W2 = (const float*)d_in[7];
    const float* b2 = (const float*)d_in[8];
    const int* src = ei;
    const int* dst = ei + N_EDGES;
    float* outp = (float*)d_out;

    // workspace carve-up (8B-aligned first)
    char* ws = (char*)d_ws;
    unsigned long long* degp = (unsigned long long*)ws;  ws += N_NODES * 8;
    float* dis      = (float*)ws;  ws += N_NODES * 4;
    float* selfnorm = (float*)ws;  ws += N_NODES * 4;
    int*   cnt      = (int*)ws;    ws += N_NODES * 4;
    int*   row      = (int*)ws;    ws += N_NODES * 4;
    int*   bsum     = (int*)ws;    ws += 512 * 4;
    int*   boff     = (int*)ws;    ws += 512 * 4;
    int2*  csr      = (int2*)ws;   ws += (size_t)N_EDGES * 8;
    f16*   xh       = (f16*)ws;    ws += (size_t)N_NODES * F_IN * 2;
    f16*   Wt0      = (f16*)ws;    ws += F_IN * HID * 2;
    f16*   Wt1      = (f16*)ws;    ws += HID * HID * 2;
    f16*   Wt2      = (f16*)ws;    ws += HID * NCLS * 2;
    f16*   bufA     = (f16*)ws;    ws += (size_t)N_NODES * HID * 2;
    f16*   bufB     = (f16*)ws;    ws += (size_t)N_NODES * HID * 2;

    const int nb = (N_NODES + 255) / 256;
    const int eb = (N_EDGES + 255) / 256;

    // ---- norm + CSR build ----
    k_init<<<nb, 256, 0, stream>>>(degp, N_NODES);
    k_deg<<<eb, 256, 0, stream>>>(dst, ew, degp, N_EDGES);
    k_dis<<<nb, 256, 0, stream>>>(degp, dis, selfnorm, cnt, N_NODES);
    k_scan1<<<nb, 256, 0, stream>>>(cnt, row, bsum, N_NODES);
    k_scan2<<<1, 512, 0, stream>>>(bsum, boff, nb);
    k_scan3<<<nb, 256, 0, stream>>>(row, cnt, boff, N_NODES);
    k_scatter<<<eb, 256, 0, stream>>>(src, dst, ew, dis, row, csr, N_EDGES);

    // ---- fp16 conversions ----
    k_f32_to_f16<<<(N_NODES * (F_IN / 4) + 255) / 256, 256, 0, stream>>>(x, xh, N_NODES * (F_IN / 4));
    k_wt<<<(F_IN * HID + 255) / 256, 256, 0, stream>>>(W0, Wt0, F_IN, HID);
    k_wt<<<(HID * HID + 255) / 256, 256, 0, stream>>>(W1, Wt1, HID, HID);
    k_wt<<<(HID * NCLS + 255) / 256, 256, 0, stream>>>(W2, Wt2, HID, NCLS);

    const int gX = (N_NODES + 127) / 128;

    // ---- layer 1: g1 = A*X (128-wide gather), H1 = relu(g1 @ W0 + b0) ----
    agg_csr<F_IN, 16, false, false><<<(N_NODES + 15) / 16, 256, 0, stream>>>(
        xh, csr, row, cnt, selfnorm, nullptr, bufA, N_NODES);
    gemm_mfma<F_IN, HID, true><<<dim3(gX, HID / 64), 256, 0, stream>>>(bufA, Wt0, b0, bufB, N_NODES);

    // ---- layer 2: g2 = A*H1 (256-wide gather), H2 = relu(g2 @ W1 + b1) ----
    agg_csr<HID, 32, false, false><<<(N_NODES + 7) / 8, 256, 0, stream>>>(
        bufB, csr, row, cnt, selfnorm, nullptr, bufA, N_NODES);
    gemm_mfma<HID, HID, true><<<dim3(gX, HID / 64), 256, 0, stream>>>(bufA, Wt1, b1, bufB, N_NODES);

    // ---- layer 3: P = H2 @ W2 (no act), out = A*P + b2 (64-wide gather) ----
    gemm_mfma<HID, NCLS, false><<<dim3(gX, NCLS / 64), 256, 0, stream>>>(bufB, Wt2, nullptr, bufA, N_NODES);
    agg_csr<NCLS, 8, true, true><<<(N_NODES + 31) / 32, 256, 0, stream>>>(
        bufA, csr, row, cnt, selfnorm, b2, outp, N_NODES);
}